// Round 5
// baseline (1166.843 us; speedup 1.0000x reference)
//
#include <hip/hip_runtime.h>
#include <stdint.h>

#define RTILE 4096
#define ROUNDS 10

// counters: [1]=M, [2]=group total, [3]=E', [4]=rmax, [7]=const 1 (ON gate),
// [8..8+ROUNDS-1]=per-round unmasked count, [32..35]=pair-sort pass gates,
// [36]=sh (cluster-id bit width), [37]=result-buffer parity (1 => keyB/payB)

// ============================ init ============================
__global__ void k_init_counters(int* counters){
  int t = threadIdx.x;
  counters[t] = 0;
  if (t == 7) counters[7] = 1;
}
__global__ void k_init_nodes(int* mis, int* cur, int* cnt, int N){
  int v = blockIdx.x*blockDim.x + threadIdx.x;
  if (v < N){ mis[v]=0; cur[v]=0; }
  if (v <= N) cnt[v]=0;
}
__global__ void k_zero_vals(float* vals, int E){
  int i = blockIdx.x*blockDim.x + threadIdx.x;
  if (i < E) vals[i]=0.f;
}

// ============================ key-making ============================
__global__ void k_score_key(const float* score, unsigned* keys, unsigned* pay, int N){
  int i = blockIdx.x*blockDim.x+threadIdx.x;
  if (i<N){
    unsigned b = __float_as_uint(score[i]);
    b ^= ((int)b < 0) ? 0xFFFFFFFFu : 0x80000000u;
    keys[i]=b; pay[i]=(unsigned)i;
  }
}
__global__ void k_rank_build(const unsigned* pay, int* rank, int* pm, int N){
  int p = blockIdx.x*blockDim.x+threadIdx.x;
  if (p<N){ int v = (int)pay[p]; rank[v]=p; pm[v]=p; }
}

// ============================ CSR via counting sort (order-free) ============================
__global__ void k_csr_count(const int* __restrict__ col, int* __restrict__ cnt, int E){
  int e = blockIdx.x*blockDim.x+threadIdx.x;
  if (e<E) atomicAdd(&cnt[col[e]], 1);
}
__global__ void k_csr_fill(const int* __restrict__ row, const int* __restrict__ col,
                           const unsigned* __restrict__ off, int* __restrict__ cur,
                           int* __restrict__ csr_row, int E){
  int e = blockIdx.x*blockDim.x+threadIdx.x;
  if (e<E){
    int c = col[e];
    int p = atomicAdd(&cur[c], 1);
    csr_row[off[c] + p] = row[e];
  }
}

// ============================ radix sort: hist + LDS-staged scatter (9-bit) ============================
template<typename K, int TILE>
__global__ void k_radix_hist(const K* __restrict__ keys, int n, int shift,
                             unsigned* __restrict__ ghist, int numBlocks, const int* gate){
  if (*gate==0) return;
  __shared__ unsigned h[512];
  int t=threadIdx.x, b=blockIdx.x;
  h[t]=0; h[t+256]=0; __syncthreads();
  int base = b*TILE;
  for (int j=t; j<TILE; j+=256){
    int i = base+j;
    if (i<n){
      unsigned d = (unsigned)((keys[i]>>shift)&(K)511);
      atomicAdd(&h[d],1u);
    }
  }
  __syncthreads();
  ghist[(size_t)t*numBlocks + b] = h[t];
  ghist[(size_t)(t+256)*numBlocks + b] = h[t+256];
}

// Stable block scatter: hist -> block scan -> stage (key,pay) in LDS grouped by
// digit -> linear drain with coalesced per-digit runs to global.
template<typename K, int TILE>
__global__ void k_radix_scatter(const K* __restrict__ keysIn, const unsigned* __restrict__ payIn,
                                K* __restrict__ keysOut, unsigned* __restrict__ payOut,
                                int n, int shift, const unsigned* __restrict__ gbase,
                                int numBlocks, const int* gate){
  if (*gate==0) return;
  __shared__ unsigned lbase[512];
  __shared__ unsigned carry[512];
  __shared__ unsigned ss[256];
  __shared__ K        skey[TILE];
  __shared__ unsigned spay[TILE];
  int t=threadIdx.x, b=blockIdx.x;
  int base = b*TILE;
  int cnt = min(TILE, n-base);
  // phase A: local histogram (into carry)
  carry[t]=0; carry[t+256]=0; __syncthreads();
  for (int c=0;c<TILE/256;++c){
    int i = base+c*256+t;
    if (i<n){
      unsigned d = (unsigned)((keysIn[i]>>shift)&(K)511);
      atomicAdd(&carry[d],1u);
    }
  }
  __syncthreads();
  // phase B: exclusive scan over 512 bins (2 per thread)
  unsigned a0=carry[2*t], a1=carry[2*t+1];
  ss[t]=a0+a1; __syncthreads();
  for (int off=1; off<256; off<<=1){
    unsigned x = (t>=off)? ss[t-off]:0u; __syncthreads();
    ss[t]+=x; __syncthreads();
  }
  unsigned excl = t? ss[t-1]:0u;
  __syncthreads();
  lbase[2*t]=excl;      lbase[2*t+1]=excl+a0;
  carry[2*t]=excl;      carry[2*t+1]=excl+a0;
  __syncthreads();
  // phase C: stable rank + stage into LDS
  int lane = t&63, wave = t>>6;
  for (int c=0;c<TILE/256;++c){
    int i = base + c*256 + t;
    bool valid = i<n;
    K k = valid ? keysIn[i] : (K)0;
    unsigned pay = valid ? payIn[i] : 0u;
    unsigned d = (unsigned)((k>>shift)&(K)511);
    unsigned off=0;
    for (int w=0; w<4; ++w){
      if (wave==w){
        unsigned long long m = __ballot(valid);
        #pragma unroll
        for (int bit=0; bit<9; ++bit){
          unsigned long long bb = __ballot((d>>bit)&1u);
          m &= ((d>>bit)&1u) ? bb : ~bb;
        }
        int lr = __popcll(m & ((1ull<<lane)-1ull));
        unsigned cb = carry[d];
        off = cb + (unsigned)lr;
        if (valid && lr==0) carry[d] = cb + (unsigned)__popcll(m);
      }
      __syncthreads();
    }
    if (valid){ skey[off]=k; spay[off]=pay; }
  }
  __syncthreads();
  // phase D: linear drain -> coalesced global writes
  for (int c=0;c<TILE/256;++c){
    int j = c*256 + t;
    if (j<cnt){
      K k = skey[j];
      unsigned d = (unsigned)((k>>shift)&(K)511);
      unsigned gpos = gbase[(size_t)d*numBlocks + b] + ((unsigned)j - lbase[d]);
      keysOut[gpos]=k; payOut[gpos]=spay[j];
    }
  }
}

// single-block exclusive scan (in-place)
__global__ void k_scan_single(unsigned* data, int n, unsigned* total, const int* gate){
  if (*gate==0) return;
  __shared__ unsigned sh[1024];
  __shared__ unsigned carry;
  int t=threadIdx.x;
  if (t==0) carry=0;
  __syncthreads();
  for (int base=0; base<n; base+=4096){
    unsigned v[4]; unsigned s=0;
    int i0 = base + t*4;
    #pragma unroll
    for (int j=0;j<4;j++){ int i=i0+j; v[j] = (i<n)?data[i]:0u; s+=v[j]; }
    sh[t]=s; __syncthreads();
    for (int off=1; off<1024; off<<=1){
      unsigned x = (t>=off)? sh[t-off]:0u; __syncthreads();
      sh[t]+=x; __syncthreads();
    }
    unsigned excl = (t?sh[t-1]:0u) + carry;
    #pragma unroll
    for (int j=0;j<4;j++){ int i=i0+j; if(i<n){ unsigned o=v[j]; data[i]=excl; excl+=o; } }
    unsigned tot = sh[1023];
    __syncthreads();
    if (t==0) carry += tot;
    __syncthreads();
  }
  if (total && t==0) *total = carry;
}

// 3-kernel big exclusive scan
__global__ void k_scan_partials(const unsigned* __restrict__ in, unsigned* __restrict__ bsums,
                                int n, const int* gate){
  if (*gate==0) return;
  __shared__ unsigned sh[256];
  int b=blockIdx.x, t=threadIdx.x;
  long base = (long)b*RTILE + (long)t*16;
  unsigned s=0;
  #pragma unroll
  for (int j=0;j<16;j++){ long i=base+j; if(i<n) s+=in[i]; }
  sh[t]=s; __syncthreads();
  for (int off=128; off>0; off>>=1){ if(t<off) sh[t]+=sh[t+off]; __syncthreads(); }
  if (t==0) bsums[b]=sh[0];
}
__global__ void k_scan_final(const unsigned* __restrict__ in, unsigned* __restrict__ out,
                             const unsigned* __restrict__ bsums, int n, const int* gate){
  if (*gate==0) return;
  __shared__ unsigned sh[256];
  int b=blockIdx.x, t=threadIdx.x;
  long base = (long)b*RTILE + (long)t*16;
  unsigned v[16]; unsigned s=0;
  #pragma unroll
  for (int j=0;j<16;j++){ long i=base+j; v[j]=(i<n)?in[i]:0u; s+=v[j]; }
  sh[t]=s; __syncthreads();
  for (int off=1; off<256; off<<=1){
    unsigned x=(t>=off)?sh[t-off]:0u; __syncthreads(); sh[t]+=x; __syncthreads();
  }
  unsigned run=(t?sh[t-1]:0u)+bsums[b];
  #pragma unroll
  for (int j=0;j<16;j++){ long i=base+j; if(i<n){ unsigned o=v[j]; out[i]=run; run+=o; } }
}

// ============================ MIS rounds (gather form; pm[v]=mask?N:rank) ============================
__global__ void k_round1(const int* __restrict__ off, const int* __restrict__ nbr,
                         const int* __restrict__ pm, int* __restrict__ mis,
                         int* __restrict__ maskA, int N, const int* gate){
  if (*gate==0) return;
  int v = blockIdx.x*blockDim.x+threadIdx.x;
  if (v>=N) return;
  int p = pm[v];
  if (p == N){ maskA[v]=1; return; }
  int m = p;
  int s=off[v], e=off[v+1];
  for (int j=s; j<e; ++j){ int u=nbr[j]; m = min(m, pm[u]); }
  int nm = (m == p);
  if (nm) mis[v]=1;
  maskA[v] = nm;
}
__global__ void k_round2(const int* __restrict__ off, const int* __restrict__ nbr,
                         const int* __restrict__ maskA, int* __restrict__ pm,
                         int N, int* cnt, const int* gate){
  if (*gate==0) return;
  int v = blockIdx.x*blockDim.x+threadIdx.x;
  int um = 0;
  if (v<N){
    int mk = maskA[v];
    int s=off[v], e=off[v+1];
    for (int j=s; j<e && !mk; ++j) mk |= maskA[nbr[j]];
    if (mk) pm[v] = N;
    um = !mk;
  }
  unsigned long long bm = __ballot(um);
  if ((threadIdx.x&63)==0 && bm) atomicAdd(cnt, (int)__popcll(bm));
}

// ============================ clustering ============================
__global__ void k_cl_init(const int* rank, const int* mis, int* pm, int N){
  int v = blockIdx.x*blockDim.x+threadIdx.x;
  if (v<N) pm[v] = mis[v] ? rank[v] : N;
}
__global__ void k_cl_gather(const int* __restrict__ off, const int* __restrict__ nbr,
                            const int* __restrict__ pm, int* __restrict__ mn, int N){
  int v = blockIdx.x*blockDim.x+threadIdx.x;
  if (v>=N) return;
  int m = pm[v];
  int s=off[v], e=off[v+1];
  for (int j=s; j<e; ++j) m = min(m, pm[nbr[j]]);
  mn[v] = m;
}
__global__ void k_copy_u32(const int* in, unsigned* out, int N){
  int v = blockIdx.x*blockDim.x+threadIdx.x;
  if (v<N) out[v]=(unsigned)in[v];
}
__global__ void k_cl_map(const int* rank, const int* mis, const unsigned* cidx,
                         int* map, int* rmax, int N){
  int v = blockIdx.x*blockDim.x+threadIdx.x;
  if (v<N && mis[v]){ map[rank[v]] = (int)cidx[v]; atomicMax(rmax, rank[v]); }
}
__global__ void k_cl_cluster(const int* mn, const int* map, const int* rmax, int* cluster, int N){
  int v = blockIdx.x*blockDim.x+threadIdx.x;
  if (v<N){
    int mr = mn[v];
    if (mr >= N) mr = *rmax;                // JAX OOB-gather clamp semantics
    cluster[v] = map[mr];
  }
}
__global__ void k_gather_x(const float4* __restrict__ x, float4* __restrict__ out,
                           const int* __restrict__ mis, const unsigned* __restrict__ cidx,
                           int N, int D4){
  int t = blockIdx.x*blockDim.x+threadIdx.x;
  int v = t / D4, q = t - v*D4;
  if (v<N && mis[v]) out[(size_t)cidx[v]*D4 + q] = x[(size_t)v*D4 + q];
}

// ============================ coarsened-edge aggregation ============================
__global__ void k_set_gates(int* counters){
  int M = counters[1];
  int sh = (M<=1) ? 1 : (32-__clz((unsigned)(M-1)));
  int kb = 2*sh;
  int npass = 1 + (9<kb) + (18<kb) + (27<kb);
  counters[36] = sh;
  counters[32] = 1;
  counters[33] = (9  < kb);
  counters[34] = (18 < kb);
  counters[35] = (27 < kb);
  counters[37] = npass & 1;                 // 1 => final data in keyB/payB
}
__global__ void k_pair_key(const int* __restrict__ row, const int* __restrict__ col,
                           const int* __restrict__ cluster, const float* __restrict__ attr,
                           unsigned long long* __restrict__ keys, unsigned* __restrict__ pay,
                           const int* __restrict__ counters, int E){
  int e = blockIdx.x*blockDim.x+threadIdx.x;
  if (e<E){
    int sh = counters[36];
    unsigned a = (unsigned)cluster[row[e]], b=(unsigned)cluster[col[e]];
    keys[e] = ((unsigned long long)a<<sh) | b;
    pay[e] = __float_as_uint(attr[e]);
  }
}
__global__ void k_flags(const unsigned long long* __restrict__ keyA,
                        const unsigned long long* __restrict__ keyB,
                        unsigned* __restrict__ fhead, unsigned* __restrict__ fkeep,
                        const int* __restrict__ counters, int E){
  const unsigned long long* keys = counters[37] ? keyB : keyA;
  int i = blockIdx.x*blockDim.x+threadIdx.x;
  if (i<E){
    int sh = counters[36];
    unsigned long long k = keys[i];
    unsigned head = (i==0) || (k != keys[i-1]);
    unsigned a=(unsigned)(k>>sh), b=(unsigned)(k & ((1ull<<sh)-1ull));
    fhead[i]=head;
    fkeep[i]=(head && a!=b) ? 1u : 0u;
  }
}
__global__ void k_acc_seg(const unsigned long long* __restrict__ keyA,
                          const unsigned long long* __restrict__ keyB,
                          const unsigned* __restrict__ payA, const unsigned* __restrict__ payB,
                          const unsigned* __restrict__ excl1,
                          float* __restrict__ vals, const int* __restrict__ counters, int E){
  const unsigned long long* keys = counters[37] ? keyB : keyA;
  const unsigned* pay = counters[37] ? payB : payA;
  int i = blockIdx.x*blockDim.x+threadIdx.x;
  int lane = threadIdx.x & 63;
  bool valid = i < E;
  unsigned long long k = valid ? keys[i] : ~0ull;
  float v = valid ? __uint_as_float(pay[i]) : 0.f;
  #pragma unroll
  for (int off=1; off<64; off<<=1){
    float o = __shfl_up(v, off);
    unsigned long long ko = __shfl_up(k, off);
    if (lane >= off && ko == k) v += o;
  }
  if (valid){
    unsigned long long knext = (i+1<E) ? keys[i+1] : ~0ull;
    if (lane==63 || k != knext){
      unsigned head = (i==0) || (keys[i-1] != k);
      atomicAdd(&vals[excl1[i] + head - 1u], v);
    }
  }
}
__global__ void k_write_edges(const unsigned long long* __restrict__ keyA,
                              const unsigned long long* __restrict__ keyB,
                              const unsigned* __restrict__ excl1, const unsigned* __restrict__ excl2,
                              const float* __restrict__ vals, float* __restrict__ out,
                              const int* __restrict__ counters, int E, int D){
  const unsigned long long* keys = counters[37] ? keyB : keyA;
  int i = blockIdx.x*blockDim.x+threadIdx.x;
  if (i<E){
    int sh = counters[36];
    int head=(i==0)||(keys[i]!=keys[i-1]);
    unsigned a=(unsigned)(keys[i]>>sh), b=(unsigned)(keys[i] & ((1ull<<sh)-1ull));
    if (head && a!=b){
      unsigned opos = excl2[i];
      int M = counters[1], Ep = counters[3];
      size_t off = (size_t)M*D;
      out[off + opos] = (float)a;
      out[off + (size_t)Ep + opos] = (float)b;
      out[off + 2*(size_t)Ep + opos] = vals[excl1[i]];
    }
  }
}
__global__ void k_write_nodes(const int* __restrict__ cluster, const int* __restrict__ mis,
                              const float* __restrict__ score, float* __restrict__ out,
                              const int* __restrict__ counters, int N, int D){
  int v = blockIdx.x*blockDim.x+threadIdx.x;
  if (v<N){
    int M=counters[1], Ep=counters[3];
    size_t off = (size_t)M*D + 3*(size_t)Ep;
    out[off + v] = (float)cluster[v];
    out[off + (size_t)N + v] = mis[v] ? 1.f : 0.f;
    out[off + 2*(size_t)N + v] = score[v];
  }
}

// ============================ host ============================
extern "C" void kernel_launch(void* const* d_in, const int* in_sizes, int n_in,
                              void* d_out, int out_size, void* d_ws, size_t ws_size,
                              hipStream_t stream){
  const float* x     = (const float*)d_in[0];
  const int*   ei    = (const int*)d_in[1];
  const float* attr  = (const float*)d_in[2];
  const float* score = (const float*)d_in[3];
  int N = in_sizes[3];
  int E = in_sizes[2];
  int D = in_sizes[0]/N;
  const int* row = ei;
  const int* col = ei + E;
  float* out = (float*)d_out;

  char* p = (char*)d_ws;
  auto alloc = [&](size_t bytes)->char*{ char* r=p; p += ((bytes+255)/256)*256; return r; };
  unsigned long long* keyA = (unsigned long long*)alloc((size_t)E*8);
  unsigned long long* keyB = (unsigned long long*)alloc((size_t)E*8);
  unsigned* payA  = (unsigned*)alloc((size_t)E*4);
  unsigned* payB  = (unsigned*)alloc((size_t)E*4);
  unsigned* scanA = (unsigned*)alloc((size_t)E*4);
  unsigned* scanB = (unsigned*)alloc((size_t)E*4);
  float*    vals  = (float*)alloc((size_t)E*4);
  int* csr_row = (int*)alloc((size_t)E*4);
  unsigned* off= (unsigned*)alloc((size_t)(N+1)*4);   // counts -> scanned offsets
  int* cur     = (int*)alloc((size_t)N*4);
  int* rank   = (int*)alloc((size_t)N*4);
  int* pm     = (int*)alloc((size_t)N*4);
  int* mis    = (int*)alloc((size_t)N*4);
  int* maskA  = (int*)alloc((size_t)N*4);
  int* mnArr  = (int*)alloc((size_t)N*4);
  int* map    = (int*)alloc((size_t)N*4);
  unsigned* cidx = (unsigned*)alloc((size_t)N*4);
  int* cluster= (int*)alloc((size_t)N*4);
  int* counters=(int*)alloc(256*4);
  int Be = (E + RTILE-1)/RTILE;
  int Bn1k = (N + 1023)/1024;
  unsigned* ghist = (unsigned*)alloc((size_t)512*Be*4);
  unsigned* bsums = (unsigned*)alloc(4096*4);

  int nbN = (N+255)/256, nbE = (E+255)/256;
  const int* ON = counters+7;

  auto big_scan = [&](unsigned* data, int n, unsigned* total, const int* gate){
    int B = (n + RTILE-1)/RTILE;
    k_scan_partials<<<B,256,0,stream>>>(data,bsums,n,gate);
    k_scan_single<<<1,1024,0,stream>>>(bsums,B,total,gate);
    k_scan_final<<<B,256,0,stream>>>(data,data,bsums,n,gate);
  };

  k_init_counters<<<1,256,0,stream>>>(counters);
  k_init_nodes<<<nbN+1,256,0,stream>>>(mis,cur,(int*)off,N);
  k_zero_vals<<<nbE,256,0,stream>>>(vals,E);

  // ---- CSR via counting sort (neighbor order irrelevant for min/OR gathers) ----
  k_csr_count<<<nbE,256,0,stream>>>(col,(int*)off,E);
  big_scan(off,N+1,nullptr,ON);
  k_csr_fill<<<nbE,256,0,stream>>>(row,col,off,cur,csr_row,E);

  // ---- rank = stable argsort(argsort(score)), 4 passes of 9 bits, TILE=1024 ----
  k_score_key<<<nbN,256,0,stream>>>(score,(unsigned*)keyA,payA,N);
  {
    unsigned *ki=(unsigned*)keyA,*ko=(unsigned*)keyB,*pi=payA,*po=payB;
    for (int pass=0; pass<4; ++pass){
      int shift = pass*9;
      k_radix_hist<unsigned,1024><<<Bn1k,256,0,stream>>>(ki,N,shift,ghist,Bn1k,ON);
      big_scan(ghist,512*Bn1k,nullptr,ON);
      k_radix_scatter<unsigned,1024><<<Bn1k,256,0,stream>>>(ki,pi,ko,po,N,shift,ghist,Bn1k,ON);
      unsigned* tk=ki; ki=ko; ko=tk; unsigned* tp=pi; pi=po; po=tp;
    }
    k_rank_build<<<nbN,256,0,stream>>>(pi, rank, pm, N);
  }

  // ---- MIS rounds: 2 gather kernels per round, gated on convergence ----
  for (int r=0; r<ROUNDS; ++r){
    const int* gate = (r==0) ? ON : (counters + 8 + r - 1);
    int* cnt = counters + 8 + r;
    k_round1<<<nbN,256,0,stream>>>((const int*)off,csr_row,pm,mis,maskA,N,gate);
    k_round2<<<nbN,256,0,stream>>>((const int*)off,csr_row,maskA,pm,N,cnt,gate);
  }

  // ---- clustering (gather form) ----
  k_cl_init<<<nbN,256,0,stream>>>(rank,mis,pm,N);
  k_cl_gather<<<nbN,256,0,stream>>>((const int*)off,csr_row,pm,mnArr,N);
  k_copy_u32<<<nbN,256,0,stream>>>(mis,cidx,N);
  big_scan(cidx,N,(unsigned*)(counters+1),ON);     // M = #MIS
  k_cl_map<<<nbN,256,0,stream>>>(rank,mis,cidx,map,counters+4,N);
  k_cl_cluster<<<nbN,256,0,stream>>>(mnArr,map,counters+4,cluster,N);
  k_gather_x<<<(N*(D/4)+255)/256,256,0,stream>>>((const float4*)x,(float4*)out,mis,cidx,N,D/4);

  // ---- coarsened edges: dynamic-packed pair sort, gated passes, parity select ----
  k_set_gates<<<1,1,0,stream>>>(counters);
  k_pair_key<<<nbE,256,0,stream>>>(row,col,cluster,attr,keyA,payA,counters,E);
  {
    unsigned long long *ki=keyA,*ko=keyB; unsigned *pi=payA,*po=payB;
    for (int pass=0; pass<4; ++pass){
      int shift = pass*9;
      const int* g = counters + 32 + pass;
      k_radix_hist<unsigned long long,RTILE><<<Be,256,0,stream>>>(ki,E,shift,ghist,Be,g);
      big_scan(ghist,512*Be,nullptr,g);
      k_radix_scatter<unsigned long long,RTILE><<<Be,256,0,stream>>>(ki,pi,ko,po,E,shift,ghist,Be,g);
      unsigned long long* tk=ki; ki=ko; ko=tk; unsigned* tp=pi; pi=po; po=tp;
    }
    k_flags<<<nbE,256,0,stream>>>(keyA,keyB,scanA,scanB,counters,E);
    big_scan(scanA,E,(unsigned*)(counters+2),ON);
    big_scan(scanB,E,(unsigned*)(counters+3),ON);
    k_acc_seg<<<nbE,256,0,stream>>>(keyA,keyB,payA,payB,scanA,vals,counters,E);
    k_write_edges<<<nbE,256,0,stream>>>(keyA,keyB,scanA,scanB,vals,out,counters,E,D);
  }
  k_write_nodes<<<nbN,256,0,stream>>>(cluster,mis,score,out,counters,N,D);
}

// Round 6
// 1023.646 us; speedup vs baseline: 1.1399x; 1.1399x over previous
//
#include <hip/hip_runtime.h>
#include <stdint.h>

#define RTILE 4096
#define ROUNDS 10

// counters: [1]=M, [2]=group total, [3]=E', [4]=rmax, [7]=const 1 (ON gate),
// [8..8+ROUNDS-1]=per-round unmasked count, [32..35]=pair-sort pass gates,
// [36]=sh (cluster-id bit width), [37]=result-buffer parity (1 => keyB/payB)

// ============================ init ============================
__global__ void k_init_counters(int* counters){
  int t = threadIdx.x;
  counters[t] = 0;
  if (t == 7) counters[7] = 1;
}
__global__ void k_init_nodes(int* mis, int N){
  int v = blockIdx.x*blockDim.x + threadIdx.x;
  if (v < N) mis[v]=0;
}
__global__ void k_zero_vals(float* vals, int E){
  int i = blockIdx.x*blockDim.x + threadIdx.x;
  if (i < E) vals[i]=0.f;
}

// ============================ key-making ============================
__global__ void k_score_key(const float* score, unsigned* keys, unsigned* pay, int N){
  int i = blockIdx.x*blockDim.x+threadIdx.x;
  if (i<N){
    unsigned b = __float_as_uint(score[i]);
    b ^= ((int)b < 0) ? 0xFFFFFFFFu : 0x80000000u;
    keys[i]=b; pay[i]=(unsigned)i;
  }
}
__global__ void k_rank_build(const unsigned* pay, int* rank, int* pm, int N){
  int p = blockIdx.x*blockDim.x+threadIdx.x;
  if (p<N){ int v = (int)pay[p]; rank[v]=p; pm[v]=p; }
}
__global__ void k_make_colrow(const int* __restrict__ row, const int* __restrict__ col,
                              unsigned* __restrict__ keys, unsigned* __restrict__ pay, int E){
  int e = blockIdx.x*blockDim.x+threadIdx.x;
  if (e<E){ keys[e]=(unsigned)col[e]; pay[e]=(unsigned)row[e]; }
}

// ============================ radix sort: hist + LDS-staged scatter (9-bit) ============================
template<typename K, int TILE>
__global__ void k_radix_hist(const K* __restrict__ keys, int n, int shift,
                             unsigned* __restrict__ ghist, int numBlocks, const int* gate){
  if (*gate==0) return;
  __shared__ unsigned h[512];
  int t=threadIdx.x, b=blockIdx.x;
  h[t]=0; h[t+256]=0; __syncthreads();
  int base = b*TILE;
  for (int j=t; j<TILE; j+=256){
    int i = base+j;
    if (i<n){
      unsigned d = (unsigned)((keys[i]>>shift)&(K)511);
      atomicAdd(&h[d],1u);
    }
  }
  __syncthreads();
  ghist[(size_t)t*numBlocks + b] = h[t];
  ghist[(size_t)(t+256)*numBlocks + b] = h[t+256];
}

// Stable block scatter: hist -> block scan -> stage (key,pay) in LDS grouped by
// digit -> linear drain with coalesced per-digit runs to global.
template<typename K, int TILE>
__global__ void k_radix_scatter(const K* __restrict__ keysIn, const unsigned* __restrict__ payIn,
                                K* __restrict__ keysOut, unsigned* __restrict__ payOut,
                                int n, int shift, const unsigned* __restrict__ gbase,
                                int numBlocks, const int* gate){
  if (*gate==0) return;
  __shared__ unsigned lbase[512];
  __shared__ unsigned carry[512];
  __shared__ unsigned ss[256];
  __shared__ K        skey[TILE];
  __shared__ unsigned spay[TILE];
  int t=threadIdx.x, b=blockIdx.x;
  int base = b*TILE;
  int cnt = min(TILE, n-base);
  // phase A: local histogram (into carry)
  carry[t]=0; carry[t+256]=0; __syncthreads();
  for (int c=0;c<TILE/256;++c){
    int i = base+c*256+t;
    if (i<n){
      unsigned d = (unsigned)((keysIn[i]>>shift)&(K)511);
      atomicAdd(&carry[d],1u);
    }
  }
  __syncthreads();
  // phase B: exclusive scan over 512 bins (2 per thread)
  unsigned a0=carry[2*t], a1=carry[2*t+1];
  ss[t]=a0+a1; __syncthreads();
  for (int off=1; off<256; off<<=1){
    unsigned x = (t>=off)? ss[t-off]:0u; __syncthreads();
    ss[t]+=x; __syncthreads();
  }
  unsigned excl = t? ss[t-1]:0u;
  __syncthreads();
  lbase[2*t]=excl;      lbase[2*t+1]=excl+a0;
  carry[2*t]=excl;      carry[2*t+1]=excl+a0;
  __syncthreads();
  // phase C: stable rank + stage into LDS
  int lane = t&63, wave = t>>6;
  for (int c=0;c<TILE/256;++c){
    int i = base + c*256 + t;
    bool valid = i<n;
    K k = valid ? keysIn[i] : (K)0;
    unsigned pay = valid ? payIn[i] : 0u;
    unsigned d = (unsigned)((k>>shift)&(K)511);
    unsigned off=0;
    for (int w=0; w<4; ++w){
      if (wave==w){
        unsigned long long m = __ballot(valid);
        #pragma unroll
        for (int bit=0; bit<9; ++bit){
          unsigned long long bb = __ballot((d>>bit)&1u);
          m &= ((d>>bit)&1u) ? bb : ~bb;
        }
        int lr = __popcll(m & ((1ull<<lane)-1ull));
        unsigned cb = carry[d];
        off = cb + (unsigned)lr;
        if (valid && lr==0) carry[d] = cb + (unsigned)__popcll(m);
      }
      __syncthreads();
    }
    if (valid){ skey[off]=k; spay[off]=pay; }
  }
  __syncthreads();
  // phase D: linear drain -> coalesced global writes
  for (int c=0;c<TILE/256;++c){
    int j = c*256 + t;
    if (j<cnt){
      K k = skey[j];
      unsigned d = (unsigned)((k>>shift)&(K)511);
      unsigned gpos = gbase[(size_t)d*numBlocks + b] + ((unsigned)j - lbase[d]);
      keysOut[gpos]=k; payOut[gpos]=spay[j];
    }
  }
}

// single-block exclusive scan (in-place)
__global__ void k_scan_single(unsigned* data, int n, unsigned* total, const int* gate){
  if (*gate==0) return;
  __shared__ unsigned sh[1024];
  __shared__ unsigned carry;
  int t=threadIdx.x;
  if (t==0) carry=0;
  __syncthreads();
  for (int base=0; base<n; base+=4096){
    unsigned v[4]; unsigned s=0;
    int i0 = base + t*4;
    #pragma unroll
    for (int j=0;j<4;j++){ int i=i0+j; v[j] = (i<n)?data[i]:0u; s+=v[j]; }
    sh[t]=s; __syncthreads();
    for (int off=1; off<1024; off<<=1){
      unsigned x = (t>=off)? sh[t-off]:0u; __syncthreads();
      sh[t]+=x; __syncthreads();
    }
    unsigned excl = (t?sh[t-1]:0u) + carry;
    #pragma unroll
    for (int j=0;j<4;j++){ int i=i0+j; if(i<n){ unsigned o=v[j]; data[i]=excl; excl+=o; } }
    unsigned tot = sh[1023];
    __syncthreads();
    if (t==0) carry += tot;
    __syncthreads();
  }
  if (total && t==0) *total = carry;
}

// 3-kernel big exclusive scan
__global__ void k_scan_partials(const unsigned* __restrict__ in, unsigned* __restrict__ bsums,
                                int n, const int* gate){
  if (*gate==0) return;
  __shared__ unsigned sh[256];
  int b=blockIdx.x, t=threadIdx.x;
  long base = (long)b*RTILE + (long)t*16;
  unsigned s=0;
  #pragma unroll
  for (int j=0;j<16;j++){ long i=base+j; if(i<n) s+=in[i]; }
  sh[t]=s; __syncthreads();
  for (int off=128; off>0; off>>=1){ if(t<off) sh[t]+=sh[t+off]; __syncthreads(); }
  if (t==0) bsums[b]=sh[0];
}
__global__ void k_scan_final(const unsigned* __restrict__ in, unsigned* __restrict__ out,
                             const unsigned* __restrict__ bsums, int n, const int* gate){
  if (*gate==0) return;
  __shared__ unsigned sh[256];
  int b=blockIdx.x, t=threadIdx.x;
  long base = (long)b*RTILE + (long)t*16;
  unsigned v[16]; unsigned s=0;
  #pragma unroll
  for (int j=0;j<16;j++){ long i=base+j; v[j]=(i<n)?in[i]:0u; s+=v[j]; }
  sh[t]=s; __syncthreads();
  for (int off=1; off<256; off<<=1){
    unsigned x=(t>=off)?sh[t-off]:0u; __syncthreads(); sh[t]+=x; __syncthreads();
  }
  unsigned run=(t?sh[t-1]:0u)+bsums[b];
  #pragma unroll
  for (int j=0;j<16;j++){ long i=base+j; if(i<n){ unsigned o=v[j]; out[i]=run; run+=o; } }
}

// ============================ CSR offsets from sorted cols ============================
__global__ void k_build_off(const unsigned* __restrict__ scol, int* __restrict__ off, int E, int N){
  int i = blockIdx.x*blockDim.x+threadIdx.x;
  if (i>=E) return;
  int c = (int)scol[i];
  int p = (i==0) ? -1 : (int)scol[i-1];
  for (int v=p+1; v<=c; ++v) off[v]=i;
  if (i==E-1){ for (int v=c+1; v<=N; ++v) off[v]=E; }
}

// ============================ MIS rounds (gather form; pm[v]=mask?N:rank) ============================
__global__ void k_round1(const int* __restrict__ off, const int* __restrict__ nbr,
                         const int* __restrict__ pm, int* __restrict__ mis,
                         int* __restrict__ maskA, int N, const int* gate){
  if (*gate==0) return;
  int v = blockIdx.x*blockDim.x+threadIdx.x;
  if (v>=N) return;
  int p = pm[v];
  if (p == N){ maskA[v]=1; return; }
  int m = p;
  int s=off[v], e=off[v+1];
  for (int j=s; j<e; ++j){ int u=nbr[j]; m = min(m, pm[u]); }
  int nm = (m == p);
  if (nm) mis[v]=1;
  maskA[v] = nm;
}
__global__ void k_round2(const int* __restrict__ off, const int* __restrict__ nbr,
                         const int* __restrict__ maskA, int* __restrict__ pm,
                         int N, int* cnt, const int* gate){
  if (*gate==0) return;
  int v = blockIdx.x*blockDim.x+threadIdx.x;
  int um = 0;
  if (v<N){
    int mk = maskA[v];
    int s=off[v], e=off[v+1];
    for (int j=s; j<e && !mk; ++j) mk |= maskA[nbr[j]];
    if (mk) pm[v] = N;
    um = !mk;
  }
  unsigned long long bm = __ballot(um);
  if ((threadIdx.x&63)==0 && bm) atomicAdd(cnt, (int)__popcll(bm));
}

// ============================ clustering ============================
__global__ void k_cl_init(const int* rank, const int* mis, int* pm, int N){
  int v = blockIdx.x*blockDim.x+threadIdx.x;
  if (v<N) pm[v] = mis[v] ? rank[v] : N;
}
__global__ void k_cl_gather(const int* __restrict__ off, const int* __restrict__ nbr,
                            const int* __restrict__ pm, int* __restrict__ mn, int N){
  int v = blockIdx.x*blockDim.x+threadIdx.x;
  if (v>=N) return;
  int m = pm[v];
  int s=off[v], e=off[v+1];
  for (int j=s; j<e; ++j) m = min(m, pm[nbr[j]]);
  mn[v] = m;
}
__global__ void k_copy_u32(const int* in, unsigned* out, int N){
  int v = blockIdx.x*blockDim.x+threadIdx.x;
  if (v<N) out[v]=(unsigned)in[v];
}
__global__ void k_cl_map(const int* rank, const int* mis, const unsigned* cidx,
                         int* map, int* rmax, int N){
  int v = blockIdx.x*blockDim.x+threadIdx.x;
  if (v<N && mis[v]){ map[rank[v]] = (int)cidx[v]; atomicMax(rmax, rank[v]); }
}
__global__ void k_cl_cluster(const int* mn, const int* map, const int* rmax, int* cluster, int N){
  int v = blockIdx.x*blockDim.x+threadIdx.x;
  if (v<N){
    int mr = mn[v];
    if (mr >= N) mr = *rmax;                // JAX OOB-gather clamp semantics
    cluster[v] = map[mr];
  }
}
__global__ void k_gather_x(const float4* __restrict__ x, float4* __restrict__ out,
                           const int* __restrict__ mis, const unsigned* __restrict__ cidx,
                           int N, int D4){
  int t = blockIdx.x*blockDim.x+threadIdx.x;
  int v = t / D4, q = t - v*D4;
  if (v<N && mis[v]) out[(size_t)cidx[v]*D4 + q] = x[(size_t)v*D4 + q];
}

// ============================ coarsened-edge aggregation ============================
__global__ void k_set_gates(int* counters){
  int M = counters[1];
  int sh = (M<=1) ? 1 : (32-__clz((unsigned)(M-1)));
  int kb = 2*sh;
  int npass = 1 + (9<kb) + (18<kb) + (27<kb);
  counters[36] = sh;
  counters[32] = 1;
  counters[33] = (9  < kb);
  counters[34] = (18 < kb);
  counters[35] = (27 < kb);
  counters[37] = npass & 1;                 // 1 => final data in keyB/payB
}
__global__ void k_pair_key(const int* __restrict__ row, const int* __restrict__ col,
                           const int* __restrict__ cluster, const float* __restrict__ attr,
                           unsigned long long* __restrict__ keys, unsigned* __restrict__ pay,
                           const int* __restrict__ counters, int E){
  int e = blockIdx.x*blockDim.x+threadIdx.x;
  if (e<E){
    int sh = counters[36];
    unsigned a = (unsigned)cluster[row[e]], b=(unsigned)cluster[col[e]];
    keys[e] = ((unsigned long long)a<<sh) | b;
    pay[e] = __float_as_uint(attr[e]);
  }
}
__global__ void k_flags(const unsigned long long* __restrict__ keyA,
                        const unsigned long long* __restrict__ keyB,
                        unsigned* __restrict__ fhead, unsigned* __restrict__ fkeep,
                        const int* __restrict__ counters, int E){
  const unsigned long long* keys = counters[37] ? keyB : keyA;
  int i = blockIdx.x*blockDim.x+threadIdx.x;
  if (i<E){
    int sh = counters[36];
    unsigned long long k = keys[i];
    unsigned head = (i==0) || (k != keys[i-1]);
    unsigned a=(unsigned)(k>>sh), b=(unsigned)(k & ((1ull<<sh)-1ull));
    fhead[i]=head;
    fkeep[i]=(head && a!=b) ? 1u : 0u;
  }
}
__global__ void k_acc_seg(const unsigned long long* __restrict__ keyA,
                          const unsigned long long* __restrict__ keyB,
                          const unsigned* __restrict__ payA, const unsigned* __restrict__ payB,
                          const unsigned* __restrict__ excl1,
                          float* __restrict__ vals, const int* __restrict__ counters, int E){
  const unsigned long long* keys = counters[37] ? keyB : keyA;
  const unsigned* pay = counters[37] ? payB : payA;
  int i = blockIdx.x*blockDim.x+threadIdx.x;
  int lane = threadIdx.x & 63;
  bool valid = i < E;
  unsigned long long k = valid ? keys[i] : ~0ull;
  float v = valid ? __uint_as_float(pay[i]) : 0.f;
  #pragma unroll
  for (int off=1; off<64; off<<=1){
    float o = __shfl_up(v, off);
    unsigned long long ko = __shfl_up(k, off);
    if (lane >= off && ko == k) v += o;
  }
  if (valid){
    unsigned long long knext = (i+1<E) ? keys[i+1] : ~0ull;
    if (lane==63 || k != knext){
      unsigned head = (i==0) || (keys[i-1] != k);
      atomicAdd(&vals[excl1[i] + head - 1u], v);
    }
  }
}
__global__ void k_write_edges(const unsigned long long* __restrict__ keyA,
                              const unsigned long long* __restrict__ keyB,
                              const unsigned* __restrict__ excl1, const unsigned* __restrict__ excl2,
                              const float* __restrict__ vals, float* __restrict__ out,
                              const int* __restrict__ counters, int E, int D){
  const unsigned long long* keys = counters[37] ? keyB : keyA;
  int i = blockIdx.x*blockDim.x+threadIdx.x;
  if (i<E){
    int sh = counters[36];
    int head=(i==0)||(keys[i]!=keys[i-1]);
    unsigned a=(unsigned)(keys[i]>>sh), b=(unsigned)(keys[i] & ((1ull<<sh)-1ull));
    if (head && a!=b){
      unsigned opos = excl2[i];
      int M = counters[1], Ep = counters[3];
      size_t off = (size_t)M*D;
      out[off + opos] = (float)a;
      out[off + (size_t)Ep + opos] = (float)b;
      out[off + 2*(size_t)Ep + opos] = vals[excl1[i]];
    }
  }
}
__global__ void k_write_nodes(const int* __restrict__ cluster, const int* __restrict__ mis,
                              const float* __restrict__ score, float* __restrict__ out,
                              const int* __restrict__ counters, int N, int D){
  int v = blockIdx.x*blockDim.x+threadIdx.x;
  if (v<N){
    int M=counters[1], Ep=counters[3];
    size_t off = (size_t)M*D + 3*(size_t)Ep;
    out[off + v] = (float)cluster[v];
    out[off + (size_t)N + v] = mis[v] ? 1.f : 0.f;
    out[off + 2*(size_t)N + v] = score[v];
  }
}

// ============================ host ============================
extern "C" void kernel_launch(void* const* d_in, const int* in_sizes, int n_in,
                              void* d_out, int out_size, void* d_ws, size_t ws_size,
                              hipStream_t stream){
  const float* x     = (const float*)d_in[0];
  const int*   ei    = (const int*)d_in[1];
  const float* attr  = (const float*)d_in[2];
  const float* score = (const float*)d_in[3];
  int N = in_sizes[3];
  int E = in_sizes[2];
  int D = in_sizes[0]/N;
  const int* row = ei;
  const int* col = ei + E;
  float* out = (float*)d_out;

  char* p = (char*)d_ws;
  auto alloc = [&](size_t bytes)->char*{ char* r=p; p += ((bytes+255)/256)*256; return r; };
  unsigned long long* keyA = (unsigned long long*)alloc((size_t)E*8);
  unsigned long long* keyB = (unsigned long long*)alloc((size_t)E*8);
  unsigned* payA  = (unsigned*)alloc((size_t)E*4);
  unsigned* payB  = (unsigned*)alloc((size_t)E*4);
  unsigned* scanA = (unsigned*)alloc((size_t)E*4);
  unsigned* scanB = (unsigned*)alloc((size_t)E*4);
  float*    vals  = (float*)alloc((size_t)E*4);
  int* csr_row = (int*)alloc((size_t)E*4);
  unsigned* off= (unsigned*)alloc((size_t)(N+1)*4);
  int* rank   = (int*)alloc((size_t)N*4);
  int* pm     = (int*)alloc((size_t)N*4);
  int* mis    = (int*)alloc((size_t)N*4);
  int* maskA  = (int*)alloc((size_t)N*4);
  int* mnArr  = (int*)alloc((size_t)N*4);
  int* map    = (int*)alloc((size_t)N*4);
  unsigned* cidx = (unsigned*)alloc((size_t)N*4);
  int* cluster= (int*)alloc((size_t)N*4);
  int* counters=(int*)alloc(256*4);
  int Be = (E + RTILE-1)/RTILE;
  int Bn1k = (N + 1023)/1024;
  unsigned* ghist = (unsigned*)alloc((size_t)512*Be*4);
  unsigned* bsums = (unsigned*)alloc(4096*4);

  int nbN = (N+255)/256, nbE = (E+255)/256;
  const int* ON = counters+7;

  auto big_scan = [&](unsigned* data, int n, unsigned* total, const int* gate){
    int B = (n + RTILE-1)/RTILE;
    k_scan_partials<<<B,256,0,stream>>>(data,bsums,n,gate);
    k_scan_single<<<1,1024,0,stream>>>(bsums,B,total,gate);
    k_scan_final<<<B,256,0,stream>>>(data,data,bsums,n,gate);
  };

  k_init_counters<<<1,256,0,stream>>>(counters);
  k_init_nodes<<<nbN,256,0,stream>>>(mis,N);
  k_zero_vals<<<nbE,256,0,stream>>>(vals,E);

  // ---- CSR: sort (col,row) by col with 2 LDS-staged radix passes, then offsets ----
  k_make_colrow<<<nbE,256,0,stream>>>(row,col,(unsigned*)keyA,payA,E);
  k_radix_hist<unsigned,RTILE><<<Be,256,0,stream>>>((unsigned*)keyA,E,0,ghist,Be,ON);
  big_scan(ghist,512*Be,nullptr,ON);
  k_radix_scatter<unsigned,RTILE><<<Be,256,0,stream>>>((unsigned*)keyA,payA,(unsigned*)keyB,payB,E,0,ghist,Be,ON);
  k_radix_hist<unsigned,RTILE><<<Be,256,0,stream>>>((unsigned*)keyB,E,9,ghist,Be,ON);
  big_scan(ghist,512*Be,nullptr,ON);
  k_radix_scatter<unsigned,RTILE><<<Be,256,0,stream>>>((unsigned*)keyB,payB,scanA,(unsigned*)csr_row,E,9,ghist,Be,ON);
  k_build_off<<<nbE,256,0,stream>>>(scanA,(int*)off,E,N);

  // ---- rank = stable argsort(argsort(score)), 4 passes of 9 bits, TILE=1024 ----
  k_score_key<<<nbN,256,0,stream>>>(score,(unsigned*)keyA,payA,N);
  {
    unsigned *ki=(unsigned*)keyA,*ko=(unsigned*)keyB,*pi=payA,*po=payB;
    for (int pass=0; pass<4; ++pass){
      int shift = pass*9;
      k_radix_hist<unsigned,1024><<<Bn1k,256,0,stream>>>(ki,N,shift,ghist,Bn1k,ON);
      big_scan(ghist,512*Bn1k,nullptr,ON);
      k_radix_scatter<unsigned,1024><<<Bn1k,256,0,stream>>>(ki,pi,ko,po,N,shift,ghist,Bn1k,ON);
      unsigned* tk=ki; ki=ko; ko=tk; unsigned* tp=pi; pi=po; po=tp;
    }
    k_rank_build<<<nbN,256,0,stream>>>(pi, rank, pm, N);
  }

  // ---- MIS rounds: 2 gather kernels per round, gated on convergence ----
  for (int r=0; r<ROUNDS; ++r){
    const int* gate = (r==0) ? ON : (counters + 8 + r - 1);
    int* cnt = counters + 8 + r;
    k_round1<<<nbN,256,0,stream>>>((const int*)off,csr_row,pm,mis,maskA,N,gate);
    k_round2<<<nbN,256,0,stream>>>((const int*)off,csr_row,maskA,pm,N,cnt,gate);
  }

  // ---- clustering (gather form) ----
  k_cl_init<<<nbN,256,0,stream>>>(rank,mis,pm,N);
  k_cl_gather<<<nbN,256,0,stream>>>((const int*)off,csr_row,pm,mnArr,N);
  k_copy_u32<<<nbN,256,0,stream>>>(mis,cidx,N);
  big_scan(cidx,N,(unsigned*)(counters+1),ON);     // M = #MIS
  k_cl_map<<<nbN,256,0,stream>>>(rank,mis,cidx,map,counters+4,N);
  k_cl_cluster<<<nbN,256,0,stream>>>(mnArr,map,counters+4,cluster,N);
  k_gather_x<<<(N*(D/4)+255)/256,256,0,stream>>>((const float4*)x,(float4*)out,mis,cidx,N,D/4);

  // ---- coarsened edges: dynamic-packed pair sort, gated passes, parity select ----
  k_set_gates<<<1,1,0,stream>>>(counters);
  k_pair_key<<<nbE,256,0,stream>>>(row,col,cluster,attr,keyA,payA,counters,E);
  {
    unsigned long long *ki=keyA,*ko=keyB; unsigned *pi=payA,*po=payB;
    for (int pass=0; pass<4; ++pass){
      int shift = pass*9;
      const int* g = counters + 32 + pass;
      k_radix_hist<unsigned long long,RTILE><<<Be,256,0,stream>>>(ki,E,shift,ghist,Be,g);
      big_scan(ghist,512*Be,nullptr,g);
      k_radix_scatter<unsigned long long,RTILE><<<Be,256,0,stream>>>(ki,pi,ko,po,E,shift,ghist,Be,g);
      unsigned long long* tk=ki; ki=ko; ko=tk; unsigned* tp=pi; pi=po; po=tp;
    }
    k_flags<<<nbE,256,0,stream>>>(keyA,keyB,scanA,scanB,counters,E);
    big_scan(scanA,E,(unsigned*)(counters+2),ON);
    big_scan(scanB,E,(unsigned*)(counters+3),ON);
    k_acc_seg<<<nbE,256,0,stream>>>(keyA,keyB,payA,payB,scanA,vals,counters,E);
    k_write_edges<<<nbE,256,0,stream>>>(keyA,keyB,scanA,scanB,vals,out,counters,E,D);
  }
  k_write_nodes<<<nbN,256,0,stream>>>(cluster,mis,score,out,counters,N,D);
}

// Round 7
// 878.169 us; speedup vs baseline: 1.3287x; 1.1657x over previous
//
#include <hip/hip_runtime.h>
#include <stdint.h>

#define RTILE 4096
#define ROUNDS 10

// counters: [1]=M, [2]=group total, [3]=E', [4]=rmax, [7]=const 1 (ON gate),
// [8..8+ROUNDS-1]=per-round unmasked count, [32..35]=pair-sort pass gates,
// [36]=sh (cluster-id bit width), [37]=result-buffer parity (1 => keyB/payB)

// ============================ init ============================
__global__ void k_init_counters(int* counters){
  int t = threadIdx.x;
  counters[t] = 0;
  if (t == 7) counters[7] = 1;
}
__global__ void k_init_nodes(int* mis, int N){
  int v = blockIdx.x*blockDim.x + threadIdx.x;
  if (v < N) mis[v]=0;
}
__global__ void k_zero_vals(float* vals, int E){
  int i = blockIdx.x*blockDim.x + threadIdx.x;
  if (i < E) vals[i]=0.f;
}

// ============================ key-making ============================
__global__ void k_score_key(const float* score, unsigned* keys, unsigned* pay, int N){
  int i = blockIdx.x*blockDim.x+threadIdx.x;
  if (i<N){
    unsigned b = __float_as_uint(score[i]);
    b ^= ((int)b < 0) ? 0xFFFFFFFFu : 0x80000000u;
    keys[i]=b; pay[i]=(unsigned)i;
  }
}
__global__ void k_rank_build(const unsigned* pay, int* rank, int* pm, int N){
  int p = blockIdx.x*blockDim.x+threadIdx.x;
  if (p<N){ int v = (int)pay[p]; rank[v]=p; pm[v]=p; }
}
__global__ void k_make_colrow(const int* __restrict__ row, const int* __restrict__ col,
                              unsigned* __restrict__ keys, unsigned* __restrict__ pay, int E){
  int e = blockIdx.x*blockDim.x+threadIdx.x;
  if (e<E){ keys[e]=(unsigned)col[e]; pay[e]=(unsigned)row[e]; }
}

// ============================ radix sort: hist (9-bit) ============================
template<typename K, int TILE>
__global__ void k_radix_hist(const K* __restrict__ keys, int n, int shift,
                             unsigned* __restrict__ ghist, int numBlocks, const int* gate){
  if (*gate==0) return;
  __shared__ unsigned h[512];
  int t=threadIdx.x, b=blockIdx.x;
  h[t]=0; h[t+256]=0; __syncthreads();
  int base = b*TILE;
  for (int j=t; j<TILE; j+=256){
    int i = base+j;
    if (i<n){
      unsigned d = (unsigned)((keys[i]>>shift)&(K)511);
      atomicAdd(&h[d],1u);
    }
  }
  __syncthreads();
  ghist[(size_t)t*numBlocks + b] = h[t];
  ghist[(size_t)(t+256)*numBlocks + b] = h[t+256];
}

// ============ radix scatter: wave-parallel ranking, two-phase LDS drain ============
// Each wave owns a contiguous quarter of the tile with a private 512-bin
// histogram/cursor row => no cross-wave serialization, no barriers in the
// ranking loop. Keys staged+drained first, then pays re-use the SAME LDS
// buffer (offsets kept in VGPRs). Stability: lane < group < wave < block.
template<typename K, int TILE>
__global__ __launch_bounds__(256)
void k_radix_scatter(const K* __restrict__ keysIn, const unsigned* __restrict__ payIn,
                     K* __restrict__ keysOut, unsigned* __restrict__ payOut,
                     int n, int shift, const unsigned* __restrict__ gbase,
                     int numBlocks, const int* gate){
  if (*gate==0) return;
  constexpr int G = TILE/256;       // elements per thread
  constexpr int SEG = TILE/4;       // per-wave segment
  __shared__ __align__(16) char smem[(size_t)TILE*sizeof(K)];
  K* skey = (K*)smem;
  unsigned* spay = (unsigned*)smem; // aliased, used after keys are drained
  __shared__ unsigned whist[4][512];
  __shared__ unsigned lbase[512];
  __shared__ unsigned ss[256];
  int t=threadIdx.x, b=blockIdx.x;
  int lane = t&63, wave = t>>6;
  int base = b*TILE;
  int tilecnt = min(TILE, n-base);
  int segBase = base + wave*SEG;

  // phase A: per-wave zero + per-wave histogram (keys kept in registers)
  for (int j=lane; j<512; j+=64) whist[wave][j]=0;   // same-wave lockstep: no sync needed
  K keys[G]; unsigned pays[G];
  for (int g=0; g<G; ++g){
    int i = segBase + g*64 + lane;
    bool valid = i<n;
    keys[g] = valid ? keysIn[i] : (K)0;
    pays[g] = valid ? payIn[i] : 0u;
    if (valid){
      unsigned d = (unsigned)((keys[g]>>shift)&(K)511);
      atomicAdd(&whist[wave][d],1u);
    }
  }
  __syncthreads();

  // phase B: digit totals -> block exclusive scan -> per-wave cursor bases
  unsigned h0[4], h1[4], u0=0, u1=0;
  #pragma unroll
  for (int w=0;w<4;++w){ h0[w]=whist[w][2*t];   u0+=h0[w];
                         h1[w]=whist[w][2*t+1]; u1+=h1[w]; }
  ss[t]=u0+u1; __syncthreads();
  for (int off=1; off<256; off<<=1){
    unsigned x=(t>=off)?ss[t-off]:0u; __syncthreads();
    ss[t]+=x; __syncthreads();
  }
  unsigned excl = t? ss[t-1]:0u;
  lbase[2*t]=excl; lbase[2*t+1]=excl+u0;
  unsigned c0=excl, c1=excl+u0;
  #pragma unroll
  for (int w=0;w<4;++w){ whist[w][2*t]=c0;   c0+=h0[w];
                         whist[w][2*t+1]=c1; c1+=h1[w]; }
  __syncthreads();

  // phase C: ballot-match rank + per-wave cursor, stage keys into LDS
  unsigned offs[G];
  for (int g=0; g<G; ++g){
    int i = segBase + g*64 + lane;
    bool valid = i<n;
    unsigned d = (unsigned)((keys[g]>>shift)&(K)511);
    unsigned long long m = __ballot(valid);
    #pragma unroll
    for (int bit=0; bit<9; ++bit){
      unsigned long long bb = __ballot((d>>bit)&1u);
      m &= ((d>>bit)&1u) ? bb : ~bb;
    }
    if (valid){
      int lr = __popcll(m & ((1ull<<lane)-1ull));
      int leader = __ffsll((unsigned long long)m)-1;
      unsigned old=0;
      if (lr==0) old = atomicAdd(&whist[wave][d], (unsigned)__popcll(m));
      old = __shfl(old, leader);
      unsigned o = old + (unsigned)lr;
      skey[o]=keys[g]; offs[g]=o;
    }
  }
  __syncthreads();

  // phase D1: linear drain of keys -> coalesced global writes; remember gpos
  unsigned gpos_[G];
  for (int c=0;c<G;++c){
    int j=c*256+t;
    if (j<tilecnt){
      K k=skey[j];
      unsigned d=(unsigned)((k>>shift)&(K)511);
      unsigned gp = gbase[(size_t)d*numBlocks + b] + ((unsigned)j - lbase[d]);
      keysOut[gp]=k; gpos_[c]=gp;
    }
  }
  __syncthreads();
  // phase C2: stage pays into the SAME buffer
  for (int g=0; g<G; ++g){
    int i = segBase + g*64 + lane;
    if (i<n) spay[offs[g]]=pays[g];
  }
  __syncthreads();
  // phase D2: drain pays
  for (int c=0;c<G;++c){
    int j=c*256+t;
    if (j<tilecnt) payOut[gpos_[c]] = spay[j];
  }
}

// ============================ scans (templated) ============================
template<typename T>
__global__ void k_scan_single(T* data, int n, T* total, const int* gate){
  if (*gate==0) return;
  __shared__ T sh[1024];
  __shared__ T carry;
  int t=threadIdx.x;
  if (t==0) carry=(T)0;
  __syncthreads();
  for (int base=0; base<n; base+=4096){
    T v[4]; T s=(T)0;
    int i0 = base + t*4;
    #pragma unroll
    for (int j=0;j<4;j++){ int i=i0+j; v[j] = (i<n)?data[i]:(T)0; s+=v[j]; }
    sh[t]=s; __syncthreads();
    for (int off=1; off<1024; off<<=1){
      T x = (t>=off)? sh[t-off]:(T)0; __syncthreads();
      sh[t]+=x; __syncthreads();
    }
    T excl = (t?sh[t-1]:(T)0) + carry;
    #pragma unroll
    for (int j=0;j<4;j++){ int i=i0+j; if(i<n){ T o=v[j]; data[i]=excl; excl+=o; } }
    T tot = sh[1023];
    __syncthreads();
    if (t==0) carry += tot;
    __syncthreads();
  }
  if (total && t==0) *total = carry;
}
template<typename T>
__global__ void k_scan_partials(const T* __restrict__ in, T* __restrict__ bsums,
                                int n, const int* gate){
  if (*gate==0) return;
  __shared__ T sh[256];
  int b=blockIdx.x, t=threadIdx.x;
  long base = (long)b*RTILE + (long)t*16;
  T s=(T)0;
  #pragma unroll
  for (int j=0;j<16;j++){ long i=base+j; if(i<n) s+=in[i]; }
  sh[t]=s; __syncthreads();
  for (int off=128; off>0; off>>=1){ if(t<off) sh[t]+=sh[t+off]; __syncthreads(); }
  if (t==0) bsums[b]=sh[0];
}
template<typename T>
__global__ void k_scan_final(const T* __restrict__ in, T* __restrict__ out,
                             const T* __restrict__ bsums, int n, const int* gate){
  if (*gate==0) return;
  __shared__ T sh[256];
  int b=blockIdx.x, t=threadIdx.x;
  long base = (long)b*RTILE + (long)t*16;
  T v[16]; T s=(T)0;
  #pragma unroll
  for (int j=0;j<16;j++){ long i=base+j; v[j]=(i<n)?in[i]:(T)0; s+=v[j]; }
  sh[t]=s; __syncthreads();
  for (int off=1; off<256; off<<=1){
    T x=(t>=off)?sh[t-off]:(T)0; __syncthreads(); sh[t]+=x; __syncthreads();
  }
  T run=(t?sh[t-1]:(T)0)+bsums[b];
  #pragma unroll
  for (int j=0;j<16;j++){ long i=base+j; if(i<n){ T o=v[j]; out[i]=run; run+=o; } }
}

// ============================ CSR offsets from sorted cols ============================
__global__ void k_build_off(const unsigned* __restrict__ scol, int* __restrict__ off, int E, int N){
  int i = blockIdx.x*blockDim.x+threadIdx.x;
  if (i>=E) return;
  int c = (int)scol[i];
  int p = (i==0) ? -1 : (int)scol[i-1];
  for (int v=p+1; v<=c; ++v) off[v]=i;
  if (i==E-1){ for (int v=c+1; v<=N; ++v) off[v]=E; }
}

// ============================ MIS rounds (gather form; pm[v]=mask?N:rank) ============================
__global__ void k_round1(const int* __restrict__ off, const int* __restrict__ nbr,
                         const int* __restrict__ pm, int* __restrict__ mis,
                         int* __restrict__ maskA, int N, const int* gate){
  if (*gate==0) return;
  int v = blockIdx.x*blockDim.x+threadIdx.x;
  if (v>=N) return;
  int p = pm[v];
  if (p == N){ maskA[v]=1; return; }
  int m = p;
  int s=off[v], e=off[v+1];
  for (int j=s; j<e; ++j){ int u=nbr[j]; m = min(m, pm[u]); }
  int nm = (m == p);
  if (nm) mis[v]=1;
  maskA[v] = nm;
}
__global__ void k_round2(const int* __restrict__ off, const int* __restrict__ nbr,
                         const int* __restrict__ maskA, int* __restrict__ pm,
                         int N, int* cnt, const int* gate){
  if (*gate==0) return;
  int v = blockIdx.x*blockDim.x+threadIdx.x;
  int um = 0;
  if (v<N){
    int mk = maskA[v];
    int s=off[v], e=off[v+1];
    for (int j=s; j<e && !mk; ++j) mk |= maskA[nbr[j]];
    if (mk) pm[v] = N;
    um = !mk;
  }
  unsigned long long bm = __ballot(um);
  if ((threadIdx.x&63)==0 && bm) atomicAdd(cnt, (int)__popcll(bm));
}

// ============================ clustering ============================
__global__ void k_cl_init(const int* rank, const int* mis, int* pm, int N){
  int v = blockIdx.x*blockDim.x+threadIdx.x;
  if (v<N) pm[v] = mis[v] ? rank[v] : N;
}
__global__ void k_cl_gather(const int* __restrict__ off, const int* __restrict__ nbr,
                            const int* __restrict__ pm, int* __restrict__ mn, int N){
  int v = blockIdx.x*blockDim.x+threadIdx.x;
  if (v>=N) return;
  int m = pm[v];
  int s=off[v], e=off[v+1];
  for (int j=s; j<e; ++j) m = min(m, pm[nbr[j]]);
  mn[v] = m;
}
__global__ void k_copy_u32(const int* in, unsigned* out, int N){
  int v = blockIdx.x*blockDim.x+threadIdx.x;
  if (v<N) out[v]=(unsigned)in[v];
}
__global__ void k_cl_map(const int* rank, const int* mis, const unsigned* cidx,
                         int* map, int* rmax, int N){
  int v = blockIdx.x*blockDim.x+threadIdx.x;
  if (v<N && mis[v]){ map[rank[v]] = (int)cidx[v]; atomicMax(rmax, rank[v]); }
}
__global__ void k_cl_cluster(const int* mn, const int* map, const int* rmax, int* cluster, int N){
  int v = blockIdx.x*blockDim.x+threadIdx.x;
  if (v<N){
    int mr = mn[v];
    if (mr >= N) mr = *rmax;                // JAX OOB-gather clamp semantics
    cluster[v] = map[mr];
  }
}
__global__ void k_gather_x(const float4* __restrict__ x, float4* __restrict__ out,
                           const int* __restrict__ mis, const unsigned* __restrict__ cidx,
                           int N, int D4){
  int t = blockIdx.x*blockDim.x+threadIdx.x;
  int v = t / D4, q = t - v*D4;
  if (v<N && mis[v]) out[(size_t)cidx[v]*D4 + q] = x[(size_t)v*D4 + q];
}

// ============================ coarsened-edge aggregation ============================
__global__ void k_set_gates(int* counters){
  int M = counters[1];
  int sh = (M<=1) ? 1 : (32-__clz((unsigned)(M-1)));
  int kb = 2*sh;
  int npass = 1 + (9<kb) + (18<kb) + (27<kb);
  counters[36] = sh;
  counters[32] = 1;
  counters[33] = (9  < kb);
  counters[34] = (18 < kb);
  counters[35] = (27 < kb);
  counters[37] = npass & 1;                 // 1 => final data in keyB/payB
}
__global__ void k_pair_key(const int* __restrict__ row, const int* __restrict__ col,
                           const int* __restrict__ cluster, const float* __restrict__ attr,
                           unsigned long long* __restrict__ keys, unsigned* __restrict__ pay,
                           const int* __restrict__ counters, int E){
  int e = blockIdx.x*blockDim.x+threadIdx.x;
  if (e<E){
    int sh = counters[36];
    unsigned a = (unsigned)cluster[row[e]], b=(unsigned)cluster[col[e]];
    keys[e] = ((unsigned long long)a<<sh) | b;
    pay[e] = __float_as_uint(attr[e]);
  }
}
// fused flags packed into one u64: low32=head, high32=keep (scanned together)
__global__ void k_flags(const unsigned long long* __restrict__ keyA,
                        const unsigned long long* __restrict__ keyB,
                        unsigned long long* __restrict__ fcomb,
                        const int* __restrict__ counters, int E){
  const unsigned long long* keys = counters[37] ? keyB : keyA;
  int i = blockIdx.x*blockDim.x+threadIdx.x;
  if (i<E){
    int sh = counters[36];
    unsigned long long k = keys[i];
    unsigned head = (i==0) || (k != keys[i-1]);
    unsigned a=(unsigned)(k>>sh), b=(unsigned)(k & ((1ull<<sh)-1ull));
    unsigned keep = (head && a!=b) ? 1u : 0u;
    fcomb[i] = ((unsigned long long)keep<<32) | head;
  }
}
__global__ void k_acc_seg(const unsigned long long* __restrict__ keyA,
                          const unsigned long long* __restrict__ keyB,
                          const unsigned* __restrict__ payA, const unsigned* __restrict__ payB,
                          const unsigned long long* __restrict__ fcomb,
                          float* __restrict__ vals, const int* __restrict__ counters, int E){
  const unsigned long long* keys = counters[37] ? keyB : keyA;
  const unsigned* pay = counters[37] ? payB : payA;
  int i = blockIdx.x*blockDim.x+threadIdx.x;
  int lane = threadIdx.x & 63;
  bool valid = i < E;
  unsigned long long k = valid ? keys[i] : ~0ull;
  float v = valid ? __uint_as_float(pay[i]) : 0.f;
  #pragma unroll
  for (int off=1; off<64; off<<=1){
    float o = __shfl_up(v, off);
    unsigned long long ko = __shfl_up(k, off);
    if (lane >= off && ko == k) v += o;
  }
  if (valid){
    unsigned long long knext = (i+1<E) ? keys[i+1] : ~0ull;
    if (lane==63 || k != knext){
      unsigned head = (i==0) || (keys[i-1] != k);
      unsigned e1 = (unsigned)fcomb[i];
      atomicAdd(&vals[e1 + head - 1u], v);
    }
  }
}
__global__ void k_write_edges(const unsigned long long* __restrict__ keyA,
                              const unsigned long long* __restrict__ keyB,
                              const unsigned long long* __restrict__ fcomb,
                              const float* __restrict__ vals, float* __restrict__ out,
                              const int* __restrict__ counters, int E, int D){
  const unsigned long long* keys = counters[37] ? keyB : keyA;
  int i = blockIdx.x*blockDim.x+threadIdx.x;
  if (i<E){
    int sh = counters[36];
    int head=(i==0)||(keys[i]!=keys[i-1]);
    unsigned a=(unsigned)(keys[i]>>sh), b=(unsigned)(keys[i] & ((1ull<<sh)-1ull));
    if (head && a!=b){
      unsigned long long sc = fcomb[i];
      unsigned opos = (unsigned)(sc>>32);
      int M = counters[1], Ep = counters[3];
      size_t off = (size_t)M*D;
      out[off + opos] = (float)a;
      out[off + (size_t)Ep + opos] = (float)b;
      out[off + 2*(size_t)Ep + opos] = vals[(unsigned)sc];
    }
  }
}
__global__ void k_write_nodes(const int* __restrict__ cluster, const int* __restrict__ mis,
                              const float* __restrict__ score, float* __restrict__ out,
                              const int* __restrict__ counters, int N, int D){
  int v = blockIdx.x*blockDim.x+threadIdx.x;
  if (v<N){
    int M=counters[1], Ep=counters[3];
    size_t off = (size_t)M*D + 3*(size_t)Ep;
    out[off + v] = (float)cluster[v];
    out[off + (size_t)N + v] = mis[v] ? 1.f : 0.f;
    out[off + 2*(size_t)N + v] = score[v];
  }
}

// ============================ host helpers ============================
template<typename T>
static void big_scan_t(T* data, int n, T* total, const int* gate, void* bsums_raw, hipStream_t stream){
  int B = (n + RTILE-1)/RTILE;
  T* bsums = (T*)bsums_raw;
  k_scan_partials<T><<<B,256,0,stream>>>(data,bsums,n,gate);
  k_scan_single<T><<<1,1024,0,stream>>>(bsums,B,total,gate);
  k_scan_final<T><<<B,256,0,stream>>>(data,data,bsums,n,gate);
}

// ============================ host ============================
extern "C" void kernel_launch(void* const* d_in, const int* in_sizes, int n_in,
                              void* d_out, int out_size, void* d_ws, size_t ws_size,
                              hipStream_t stream){
  const float* x     = (const float*)d_in[0];
  const int*   ei    = (const int*)d_in[1];
  const float* attr  = (const float*)d_in[2];
  const float* score = (const float*)d_in[3];
  int N = in_sizes[3];
  int E = in_sizes[2];
  int D = in_sizes[0]/N;
  const int* row = ei;
  const int* col = ei + E;
  float* out = (float*)d_out;

  char* p = (char*)d_ws;
  auto alloc = [&](size_t bytes)->char*{ char* r=p; p += ((bytes+255)/256)*256; return r; };
  unsigned long long* keyA = (unsigned long long*)alloc((size_t)E*8);
  unsigned long long* keyB = (unsigned long long*)alloc((size_t)E*8);
  unsigned* payA  = (unsigned*)alloc((size_t)E*4);
  unsigned* payB  = (unsigned*)alloc((size_t)E*4);
  unsigned* scanA = (unsigned*)alloc((size_t)E*4);
  unsigned long long* fcomb = (unsigned long long*)alloc((size_t)E*8);
  float*    vals  = (float*)alloc((size_t)E*4);
  int* csr_row = (int*)alloc((size_t)E*4);
  unsigned* off= (unsigned*)alloc((size_t)(N+1)*4);
  int* rank   = (int*)alloc((size_t)N*4);
  int* pm     = (int*)alloc((size_t)N*4);
  int* mis    = (int*)alloc((size_t)N*4);
  int* maskA  = (int*)alloc((size_t)N*4);
  int* mnArr  = (int*)alloc((size_t)N*4);
  int* map    = (int*)alloc((size_t)N*4);
  unsigned* cidx = (unsigned*)alloc((size_t)N*4);
  int* cluster= (int*)alloc((size_t)N*4);
  int* counters=(int*)alloc(256*4);
  int Be = (E + RTILE-1)/RTILE;
  int Bn1k = (N + 1023)/1024;
  unsigned* ghist = (unsigned*)alloc((size_t)512*Be*4);
  void* bsums = (void*)alloc(4096*8);

  int nbN = (N+255)/256, nbE = (E+255)/256;
  const int* ON = counters+7;

  k_init_counters<<<1,256,0,stream>>>(counters);
  k_init_nodes<<<nbN,256,0,stream>>>(mis,N);
  k_zero_vals<<<nbE,256,0,stream>>>(vals,E);

  // ---- CSR: sort (col,row) by col with 2 LDS-staged radix passes, then offsets ----
  k_make_colrow<<<nbE,256,0,stream>>>(row,col,(unsigned*)keyA,payA,E);
  k_radix_hist<unsigned,RTILE><<<Be,256,0,stream>>>((unsigned*)keyA,E,0,ghist,Be,ON);
  big_scan_t<unsigned>(ghist,512*Be,nullptr,ON,bsums,stream);
  k_radix_scatter<unsigned,RTILE><<<Be,256,0,stream>>>((unsigned*)keyA,payA,(unsigned*)keyB,payB,E,0,ghist,Be,ON);
  k_radix_hist<unsigned,RTILE><<<Be,256,0,stream>>>((unsigned*)keyB,E,9,ghist,Be,ON);
  big_scan_t<unsigned>(ghist,512*Be,nullptr,ON,bsums,stream);
  k_radix_scatter<unsigned,RTILE><<<Be,256,0,stream>>>((unsigned*)keyB,payB,scanA,(unsigned*)csr_row,E,9,ghist,Be,ON);
  k_build_off<<<nbE,256,0,stream>>>(scanA,(int*)off,E,N);

  // ---- rank = stable argsort(argsort(score)), 4 passes of 9 bits, TILE=1024 ----
  k_score_key<<<nbN,256,0,stream>>>(score,(unsigned*)keyA,payA,N);
  {
    unsigned *ki=(unsigned*)keyA,*ko=(unsigned*)keyB,*pi=payA,*po=payB;
    for (int pass=0; pass<4; ++pass){
      int shift = pass*9;
      k_radix_hist<unsigned,1024><<<Bn1k,256,0,stream>>>(ki,N,shift,ghist,Bn1k,ON);
      big_scan_t<unsigned>(ghist,512*Bn1k,nullptr,ON,bsums,stream);
      k_radix_scatter<unsigned,1024><<<Bn1k,256,0,stream>>>(ki,pi,ko,po,N,shift,ghist,Bn1k,ON);
      unsigned* tk=ki; ki=ko; ko=tk; unsigned* tp=pi; pi=po; po=tp;
    }
    k_rank_build<<<nbN,256,0,stream>>>(pi, rank, pm, N);
  }

  // ---- MIS rounds: 2 gather kernels per round, gated on convergence ----
  for (int r=0; r<ROUNDS; ++r){
    const int* gate = (r==0) ? ON : (counters + 8 + r - 1);
    int* cnt = counters + 8 + r;
    k_round1<<<nbN,256,0,stream>>>((const int*)off,csr_row,pm,mis,maskA,N,gate);
    k_round2<<<nbN,256,0,stream>>>((const int*)off,csr_row,maskA,pm,N,cnt,gate);
  }

  // ---- clustering (gather form) ----
  k_cl_init<<<nbN,256,0,stream>>>(rank,mis,pm,N);
  k_cl_gather<<<nbN,256,0,stream>>>((const int*)off,csr_row,pm,mnArr,N);
  k_copy_u32<<<nbN,256,0,stream>>>(mis,cidx,N);
  big_scan_t<unsigned>(cidx,N,(unsigned*)(counters+1),ON,bsums,stream);   // M = #MIS
  k_cl_map<<<nbN,256,0,stream>>>(rank,mis,cidx,map,counters+4,N);
  k_cl_cluster<<<nbN,256,0,stream>>>(mnArr,map,counters+4,cluster,N);
  k_gather_x<<<(N*(D/4)+255)/256,256,0,stream>>>((const float4*)x,(float4*)out,mis,cidx,N,D/4);

  // ---- coarsened edges: dynamic-packed pair sort, gated passes, parity select ----
  k_set_gates<<<1,1,0,stream>>>(counters);
  k_pair_key<<<nbE,256,0,stream>>>(row,col,cluster,attr,keyA,payA,counters,E);
  {
    unsigned long long *ki=keyA,*ko=keyB; unsigned *pi=payA,*po=payB;
    for (int pass=0; pass<4; ++pass){
      int shift = pass*9;
      const int* g = counters + 32 + pass;
      k_radix_hist<unsigned long long,RTILE><<<Be,256,0,stream>>>(ki,E,shift,ghist,Be,g);
      big_scan_t<unsigned>(ghist,512*Be,nullptr,g,bsums,stream);
      k_radix_scatter<unsigned long long,RTILE><<<Be,256,0,stream>>>(ki,pi,ko,po,E,shift,ghist,Be,g);
      unsigned long long* tk=ki; ki=ko; ko=tk; unsigned* tp=pi; pi=po; po=tp;
    }
    k_flags<<<nbE,256,0,stream>>>(keyA,keyB,fcomb,counters,E);
    big_scan_t<unsigned long long>(fcomb,E,(unsigned long long*)(counters+2),ON,bsums,stream);
    k_acc_seg<<<nbE,256,0,stream>>>(keyA,keyB,payA,payB,fcomb,vals,counters,E);
    k_write_edges<<<nbE,256,0,stream>>>(keyA,keyB,fcomb,vals,out,counters,E,D);
  }
  k_write_nodes<<<nbN,256,0,stream>>>(cluster,mis,score,out,counters,N,D);
}